// Round 2
// baseline (811.523 us; speedup 1.0000x reference)
//
#include <hip/hip_runtime.h>
#include <math.h>

#define NLAT 361
#define NLON 720
#define EPSF 1e-7f
#define TWOPI_N 6.283185307179586e+0  // 2*pi; step = TWOPI_N/720

// ---------------------------------------------------------------------------
// Kernel 1: real DFT over longitude, two latitude rows per block (shared
// rotators), fused quadrature weight, output in leg-friendly layout:
//   GG[m][j][bc] = float4( Fp.re, Fp.im, Ft.re, Ft.im ) * (2pi/720) * w[j]
// m = 0..359 (Nyquist bin 360 is dead under the triangular mask).
// Thread m (0..180) produces bins m and 360-m via n-parity routing; per-lane
// incremental complex rotators replace the LDS twiddle table (no bank
// conflicts, no index ALU).
// ---------------------------------------------------------------------------
__global__ void dft_kernel(const float* __restrict__ pred,
                           const float* __restrict__ targ,
                           const float* __restrict__ wq,
                           float4* __restrict__ GG) {
  const int blk = blockIdx.x;          // 16 * 181 blocks
  const int bc  = blk / 181;
  const int p   = blk - bc * 181;
  const int j0  = 2 * p;
  const int j1  = (j0 + 1 <= 360) ? j0 + 1 : j0;   // row 360 pairs with itself

  const float* fp0 = pred + ((size_t)bc * NLAT + j0) * NLON;
  const float* ft0 = targ + ((size_t)bc * NLAT + j0) * NLON;
  const float* fp1 = pred + ((size_t)bc * NLAT + j1) * NLON;
  const float* ft1 = targ + ((size_t)bc * NLAT + j1) * NLON;

  __shared__ float4 eo[2][360];        // (e_p, o_p, e_t, o_t), n=1..359
  const int tid = threadIdx.x;
  for (int idx = tid; idx < 720; idx += 192) {
    int r = idx / 360, n = idx - 360 * r;
    if (n >= 1) {
      const float* a = r ? fp1 : fp0;
      const float* b = r ? ft1 : ft0;
      float a1 = a[n], a2 = a[NLON - n], b1 = b[n], b2 = b[NLON - n];
      eo[r][n] = make_float4(a1 + a2, a1 - a2, b1 + b2, b1 - b2);
    }
  }
  __syncthreads();

  const int m = tid;
  if (m > 180) return;

  // rotators: chain1 at angle (2k-1)*m*t0, chain2 at (2k)*m*t0; step 2m*t0
  float c1, s1, c2, s2, cs, ss;
  {
    float a1 = (float)(TWOPI_N / 720.0 * (double)m);
    float a2 = (float)(TWOPI_N / 720.0 * (double)(2 * m));
    sincosf(a1, &s1, &c1);
    sincosf(a2, &ss, &cs);
    c2 = cs; s2 = ss;
  }

  float CeP0 = 0.f, CoP0 = 0.f, SeP0 = 0.f, SoP0 = 0.f;
  float CeT0 = 0.f, CoT0 = 0.f, SeT0 = 0.f, SoT0 = 0.f;
  float CeP1 = 0.f, CoP1 = 0.f, SeP1 = 0.f, SoP1 = 0.f;
  float CeT1 = 0.f, CoT1 = 0.f, SeT1 = 0.f, SoT1 = 0.f;

#pragma unroll 2
  for (int k = 1; k <= 179; ++k) {
    float4 u0 = eo[0][2 * k - 1], v0 = eo[0][2 * k];
    float4 u1 = eo[1][2 * k - 1], v1 = eo[1][2 * k];
    CoP0 += u0.x * c1; SoP0 += u0.y * s1; CoT0 += u0.z * c1; SoT0 += u0.w * s1;
    CeP0 += v0.x * c2; SeP0 += v0.y * s2; CeT0 += v0.z * c2; SeT0 += v0.w * s2;
    CoP1 += u1.x * c1; SoP1 += u1.y * s1; CoT1 += u1.z * c1; SoT1 += u1.w * s1;
    CeP1 += v1.x * c2; SeP1 += v1.y * s2; CeT1 += v1.z * c2; SeT1 += v1.w * s2;
    float nc1 = c1 * cs - s1 * ss, ns1 = s1 * cs + c1 * ss;
    c1 = nc1; s1 = ns1;
    float nc2 = c2 * cs - s2 * ss, ns2 = s2 * cs + c2 * ss;
    c2 = nc2; s2 = ns2;
  }
  { // tail n = 359 (odd); c1,s1 now at angle 359*m*t0
    float4 u0 = eo[0][359], u1 = eo[1][359];
    CoP0 += u0.x * c1; SoP0 += u0.y * s1; CoT0 += u0.z * c1; SoT0 += u0.w * s1;
    CoP1 += u1.x * c1; SoP1 += u1.y * s1; CoT1 += u1.z * c1; SoT1 += u1.w * s1;
  }

  const float sgn = (m & 1) ? -1.f : 1.f;
  const float t0w = (float)(TWOPI_N / 720.0);
  // row 0
  {
    float baseP = fp0[0] + sgn * fp0[360];
    float baseT = ft0[0] + sgn * ft0[360];
    float sc = t0w * wq[j0];
    float reP = baseP + CeP0 + CoP0, imP = -(SeP0 + SoP0);
    float reT = baseT + CeT0 + CoT0, imT = -(SeT0 + SoT0);
    GG[((size_t)m * NLAT + j0) * 16 + bc] =
        make_float4(reP * sc, imP * sc, reT * sc, imT * sc);
    if (m >= 1 && m <= 179) {
      int m2 = 360 - m;
      float reP2 = baseP + CeP0 - CoP0, imP2 = SeP0 - SoP0;
      float reT2 = baseT + CeT0 - CoT0, imT2 = SeT0 - SoT0;
      GG[((size_t)m2 * NLAT + j0) * 16 + bc] =
          make_float4(reP2 * sc, imP2 * sc, reT2 * sc, imT2 * sc);
    }
  }
  // row 1 (duplicate write when j1==j0 is benign: same thread, same value)
  {
    float baseP = fp1[0] + sgn * fp1[360];
    float baseT = ft1[0] + sgn * ft1[360];
    float sc = t0w * wq[j1];
    float reP = baseP + CeP1 + CoP1, imP = -(SeP1 + SoP1);
    float reT = baseT + CeT1 + CoT1, imT = -(SeT1 + SoT1);
    GG[((size_t)m * NLAT + j1) * 16 + bc] =
        make_float4(reP * sc, imP * sc, reT * sc, imT * sc);
    if (m >= 1 && m <= 179) {
      int m2 = 360 - m;
      float reP2 = baseP + CeP1 - CoP1, imP2 = SeP1 - SoP1;
      float reT2 = baseT + CeT1 - CoT1, imT2 = SeT1 - SoT1;
      GG[((size_t)m2 * NLAT + j1) * 16 + bc] =
          make_float4(reP2 * sc, imP2 * sc, reT2 * sc, imT2 * sc);
    }
  }
}

// ---------------------------------------------------------------------------
// Kernel 2: Legendre contraction + triangular PSD/cross-spectrum.
// Parity trick: Pbar_lm(-x) = (-1)^(l+m) Pbar_lm(x) -> only j=0..180 read.
// Decomposition: block = 128 thr = 16 bc (lane bits 0..3, coalesced GG) x
// 4 j-lanes (bits 4..5, shfl_xor reduce) x 2 l-groups (wave id); each THREAD
// owns 8 l-rows -> 32 acc-FMAs per GG load pair, 2x redundancy (was 4x).
// Inner loop: plain counted for + unroll 2 — the compiler pipelines this
// (R1 post-mortem: manual while/prefetch caused spills, VGPR=56 < live set).
// Epilogue per-m (no persistent racc) keeps VGPR well under the
// launch_bounds(128,4) cap of 128.
// Grid = 2208 blocks (sum over 23 l-tiles of 8*(lt+1) two-m blocks).
// ---------------------------------------------------------------------------
#define ACC8()                                                       \
  do {                                                               \
    ca[0][0] += g0.x * u0x; ca[0][1] += g0.x * u0y;                  \
    ca[0][2] += g0.x * u0z; ca[0][3] += g0.x * u0w;                  \
    ca[1][0] += g0.y * u1x; ca[1][1] += g0.y * u1y;                  \
    ca[1][2] += g0.y * u1z; ca[1][3] += g0.y * u1w;                  \
    ca[2][0] += g0.z * u0x; ca[2][1] += g0.z * u0y;                  \
    ca[2][2] += g0.z * u0z; ca[2][3] += g0.z * u0w;                  \
    ca[3][0] += g0.w * u1x; ca[3][1] += g0.w * u1y;                  \
    ca[3][2] += g0.w * u1z; ca[3][3] += g0.w * u1w;                  \
    ca[4][0] += g1.x * u0x; ca[4][1] += g1.x * u0y;                  \
    ca[4][2] += g1.x * u0z; ca[4][3] += g1.x * u0w;                  \
    ca[5][0] += g1.y * u1x; ca[5][1] += g1.y * u1y;                  \
    ca[5][2] += g1.y * u1z; ca[5][3] += g1.y * u1w;                  \
    ca[6][0] += g1.z * u0x; ca[6][1] += g1.z * u0y;                  \
    ca[6][2] += g1.z * u0z; ca[6][3] += g1.z * u0w;                  \
    ca[7][0] += g1.w * u1x; ca[7][1] += g1.w * u1y;                  \
    ca[7][2] += g1.w * u1z; ca[7][3] += g1.w * u1w;                  \
  } while (0)

__global__ __launch_bounds__(128, 4)
void leg_kernel(const float* __restrict__ leg,
                const float4* __restrict__ GG,
                float* __restrict__ S) {
  int bid = blockIdx.x;
  int lt = 0, accb = 0;
  while (bid >= accb + 8 * (lt + 1)) { accb += 8 * (lt + 1); ++lt; }
  const int l0 = lt * 16;
  const int m0 = (bid - accb) * 2;

  __shared__ float sLg[181][20];   // transposed tile, stride 20 (16B-aligned,
                                   // conflict-free b128 reads)
  const int tid = threadIdx.x;
  const int bc = tid & 15;         // 0..15 (consecutive bc -> coalesced GG)
  const int jg = (tid >> 4) & 3;   // 0..3  (j-lanes: lane bits 4..5)
  const int lg = tid >> 6;         // 0..1  (l-group = wave id; rows lg*8..+7)

  for (int mi = 0; mi < 2; ++mi) {
    const int m = m0 + mi;
    if (m > 359) break;            // uniform across block
    if (mi) __syncthreads();
    // stage leg[l0..l0+15][m][0..180] transposed (coalesced global read)
    for (int idx = tid; idx < 16 * 181; idx += 128) {
      int lp = idx / 181, j = idx - lp * 181;
      int l = l0 + lp;
      sLg[j][lp] = (l <= 360) ? leg[((size_t)l * NLAT + m) * NLAT + j] : 0.f;
    }
    __syncthreads();

    // parity of row r=0 of each l-group is (l0+m)&1 (lg*8 is even).
    // u0 = A + sgn*B serves even r, u1 = A - sgn*B serves odd r.
    const float sgn  = ((l0 + m) & 1) ? -1.f : 1.f;
    const float msgn = -sgn;
    const float4* gm = GG + (size_t)m * (NLAT * 16);

    float ca[8][4];
#pragma unroll
    for (int r = 0; r < 8; ++r)
#pragma unroll
      for (int c = 0; c < 4; ++c) ca[r][c] = 0.f;

    // 45 iterations for every jg; loads at top so the compiler can
    // software-pipeline across the unrolled pair.
#pragma unroll 2
    for (int j = jg; j < 180; j += 4) {
      float4 A = gm[j * 16 + bc];
      float4 B = gm[(360 - j) * 16 + bc];
      float u0x = fmaf(sgn,  B.x, A.x), u0y = fmaf(sgn,  B.y, A.y);
      float u0z = fmaf(sgn,  B.z, A.z), u0w = fmaf(sgn,  B.w, A.w);
      float u1x = fmaf(msgn, B.x, A.x), u1y = fmaf(msgn, B.y, A.y);
      float u1z = fmaf(msgn, B.z, A.z), u1w = fmaf(msgn, B.w, A.w);
      const float* lrow = &sLg[j][lg * 8];
      float4 g0 = *(const float4*)lrow;
      float4 g1 = *(const float4*)(lrow + 4);
      ACC8();
    }
    // center j = 180 (self-paired, half weight) handled by jg==0 lanes
    if (jg == 0) {
      float4 A = gm[180 * 16 + bc];
      const float h0 = 0.5f + 0.5f * sgn;   // 1 if even parity else 0
      const float h1 = 0.5f - 0.5f * sgn;
      float u0x = h0 * A.x, u0y = h0 * A.y, u0z = h0 * A.z, u0w = h0 * A.w;
      float u1x = h1 * A.x, u1y = h1 * A.y, u1z = h1 * A.z, u1w = h1 * A.w;
      const float* lrow = &sLg[180][lg * 8];
      float4 g0 = *(const float4*)lrow;
      float4 g1 = *(const float4*)(lrow + 4);
      ACC8();
    }

    // reduce across the 4 j-lanes (lane bits 4..5)
#pragma unroll
    for (int r = 0; r < 8; ++r)
#pragma unroll
      for (int c = 0; c < 4; ++c) {
        ca[r][c] += __shfl_xor(ca[r][c], 16);
        ca[r][c] += __shfl_xor(ca[r][c], 32);
      }
    const float ef = (m == 0) ? 1.f : 2.f;
    if ((tid & 0x30) == 0) {   // jg == 0 lanes: 16 bc x 2 waves
#pragma unroll
      for (int r = 0; r < 8; ++r) {
        int l = l0 + lg * 8 + r;
        if (l < 360) {
          float pr = ca[r][0], pi = ca[r][1], tr = ca[r][2], ti = ca[r][3];
          float* sp = S + ((size_t)bc * 360 + l) * 4;
          atomicAdd(sp + 0, ef * (pr * pr + pi * pi));
          atomicAdd(sp + 1, ef * (tr * tr + ti * ti));
          atomicAdd(sp + 2, ef * (pr * tr + pi * ti));
          atomicAdd(sp + 3, ef * (pr * ti - pi * tr));
        }
      }
    }
  }
}

// ---------------------------------------------------------------------------
// Kernel 3: final loss epilogue + reduction. One block.
// ---------------------------------------------------------------------------
__global__ void loss_kernel(const float* __restrict__ S,
                            const float* __restrict__ wts,
                            float* __restrict__ out) {
  const int tid = threadIdx.x;
  float acc = 0.f;
  for (int i = tid; i < 16 * 360; i += 256) {
    int bc = i / 360;
    const float* sp = S + (size_t)i * 4;
    float pp = sp[0] + EPSF;
    float tp = sp[1] + EPSF;
    float sr = sp[2], si = sp[3];
    float mag   = sqrtf(sr * sr + si * si);
    float denom = sqrtf(pp * tp + EPSF);
    float coh   = mag / (denom + EPSF);
    coh = fminf(fmaxf(coh, 0.f), 1.f);
    float sqp = sqrtf(pp), sqt = sqrtf(tp);
    float amp = (sqp - sqt) * (sqp - sqt);
    float dec = 2.f * fmaxf(pp, tp) * (1.f - coh);
    acc += (amp + dec) * wts[bc & 7];
  }
  __shared__ float red[4];
#pragma unroll
  for (int off = 32; off > 0; off >>= 1) acc += __shfl_xor(acc, off, 64);
  if ((tid & 63) == 0) red[tid >> 6] = acc;
  __syncthreads();
  if (tid == 0) {
    float loss = (red[0] + red[1] + red[2] + red[3]) / (360.f * 16.f);
    out[0] = isnan(loss) ? 1e6f : loss;
  }
}

// ---------------------------------------------------------------------------
extern "C" void kernel_launch(void* const* d_in, const int* in_sizes, int n_in,
                              void* d_out, int out_size, void* d_ws, size_t ws_size,
                              hipStream_t stream) {
  const float* pred = (const float*)d_in[0];   // [2,8,361,720]
  const float* targ = (const float*)d_in[1];   // [2,8,361,720]
  const float* wts  = (const float*)d_in[2];   // [8]
  const float* leg  = (const float*)d_in[3];   // [361,361,361]
  const float* wq   = (const float*)d_in[4];   // [361]
  float* out = (float*)d_out;

  float4* GG = (float4*)d_ws;                            // [360][361][16] float4
  float*  S  = (float*)(GG + (size_t)360 * NLAT * 16);   // [16][360][4]

  hipMemsetAsync(S, 0, (size_t)16 * 360 * 4 * sizeof(float), stream);

  dft_kernel<<<16 * 181, 192, 0, stream>>>(pred, targ, wq, GG);

  // 2208 = sum over 23 l-tiles of 8*(lt+1) m-blocks (2 m each)
  leg_kernel<<<2208, 128, 0, stream>>>(leg, GG, S);

  loss_kernel<<<1, 256, 0, stream>>>(S, wts, out);
}

// Round 3
// 505.877 us; speedup vs baseline: 1.6042x; 1.6042x over previous
//
#include <hip/hip_runtime.h>
#include <math.h>

#define NLAT 361
#define NLON 720
#define EPSF 1e-7f
#define TWOPI_N 6.283185307179586e+0  // 2*pi; step = TWOPI_N/720

// ---------------------------------------------------------------------------
// Kernel 1: real DFT over longitude, two latitude rows per block (shared
// rotators), fused quadrature weight, output in leg-friendly layout:
//   GG[m][j][bc] = float4( Fp.re, Fp.im, Ft.re, Ft.im ) * (2pi/720) * w[j]
// m = 0..359 (Nyquist bin 360 is dead under the triangular mask).
// Thread m (0..180) produces bins m and 360-m via n-parity routing; per-lane
// incremental complex rotators replace the LDS twiddle table (no bank
// conflicts, no index ALU).
// ---------------------------------------------------------------------------
__global__ void dft_kernel(const float* __restrict__ pred,
                           const float* __restrict__ targ,
                           const float* __restrict__ wq,
                           float4* __restrict__ GG) {
  const int blk = blockIdx.x;          // 16 * 181 blocks
  const int bc  = blk / 181;
  const int p   = blk - bc * 181;
  const int j0  = 2 * p;
  const int j1  = (j0 + 1 <= 360) ? j0 + 1 : j0;   // row 360 pairs with itself

  const float* fp0 = pred + ((size_t)bc * NLAT + j0) * NLON;
  const float* ft0 = targ + ((size_t)bc * NLAT + j0) * NLON;
  const float* fp1 = pred + ((size_t)bc * NLAT + j1) * NLON;
  const float* ft1 = targ + ((size_t)bc * NLAT + j1) * NLON;

  __shared__ float4 eo[2][360];        // (e_p, o_p, e_t, o_t), n=1..359
  const int tid = threadIdx.x;
  for (int idx = tid; idx < 720; idx += 192) {
    int r = idx / 360, n = idx - 360 * r;
    if (n >= 1) {
      const float* a = r ? fp1 : fp0;
      const float* b = r ? ft1 : ft0;
      float a1 = a[n], a2 = a[NLON - n], b1 = b[n], b2 = b[NLON - n];
      eo[r][n] = make_float4(a1 + a2, a1 - a2, b1 + b2, b1 - b2);
    }
  }
  __syncthreads();

  const int m = tid;
  if (m > 180) return;

  // rotators: chain1 at angle (2k-1)*m*t0, chain2 at (2k)*m*t0; step 2m*t0
  float c1, s1, c2, s2, cs, ss;
  {
    float a1 = (float)(TWOPI_N / 720.0 * (double)m);
    float a2 = (float)(TWOPI_N / 720.0 * (double)(2 * m));
    sincosf(a1, &s1, &c1);
    sincosf(a2, &ss, &cs);
    c2 = cs; s2 = ss;
  }

  float CeP0 = 0.f, CoP0 = 0.f, SeP0 = 0.f, SoP0 = 0.f;
  float CeT0 = 0.f, CoT0 = 0.f, SeT0 = 0.f, SoT0 = 0.f;
  float CeP1 = 0.f, CoP1 = 0.f, SeP1 = 0.f, SoP1 = 0.f;
  float CeT1 = 0.f, CoT1 = 0.f, SeT1 = 0.f, SoT1 = 0.f;

#pragma unroll 2
  for (int k = 1; k <= 179; ++k) {
    float4 u0 = eo[0][2 * k - 1], v0 = eo[0][2 * k];
    float4 u1 = eo[1][2 * k - 1], v1 = eo[1][2 * k];
    CoP0 += u0.x * c1; SoP0 += u0.y * s1; CoT0 += u0.z * c1; SoT0 += u0.w * s1;
    CeP0 += v0.x * c2; SeP0 += v0.y * s2; CeT0 += v0.z * c2; SeT0 += v0.w * s2;
    CoP1 += u1.x * c1; SoP1 += u1.y * s1; CoT1 += u1.z * c1; SoT1 += u1.w * s1;
    CeP1 += v1.x * c2; SeP1 += v1.y * s2; CeT1 += v1.z * c2; SeT1 += v1.w * s2;
    float nc1 = c1 * cs - s1 * ss, ns1 = s1 * cs + c1 * ss;
    c1 = nc1; s1 = ns1;
    float nc2 = c2 * cs - s2 * ss, ns2 = s2 * cs + c2 * ss;
    c2 = nc2; s2 = ns2;
  }
  { // tail n = 359 (odd); c1,s1 now at angle 359*m*t0
    float4 u0 = eo[0][359], u1 = eo[1][359];
    CoP0 += u0.x * c1; SoP0 += u0.y * s1; CoT0 += u0.z * c1; SoT0 += u0.w * s1;
    CoP1 += u1.x * c1; SoP1 += u1.y * s1; CoT1 += u1.z * c1; SoT1 += u1.w * s1;
  }

  const float sgn = (m & 1) ? -1.f : 1.f;
  const float t0w = (float)(TWOPI_N / 720.0);
  // row 0
  {
    float baseP = fp0[0] + sgn * fp0[360];
    float baseT = ft0[0] + sgn * ft0[360];
    float sc = t0w * wq[j0];
    float reP = baseP + CeP0 + CoP0, imP = -(SeP0 + SoP0);
    float reT = baseT + CeT0 + CoT0, imT = -(SeT0 + SoT0);
    GG[((size_t)m * NLAT + j0) * 16 + bc] =
        make_float4(reP * sc, imP * sc, reT * sc, imT * sc);
    if (m >= 1 && m <= 179) {
      int m2 = 360 - m;
      float reP2 = baseP + CeP0 - CoP0, imP2 = SeP0 - SoP0;
      float reT2 = baseT + CeT0 - CoT0, imT2 = SeT0 - SoT0;
      GG[((size_t)m2 * NLAT + j0) * 16 + bc] =
          make_float4(reP2 * sc, imP2 * sc, reT2 * sc, imT2 * sc);
    }
  }
  // row 1 (duplicate write when j1==j0 is benign: same thread, same value)
  {
    float baseP = fp1[0] + sgn * fp1[360];
    float baseT = ft1[0] + sgn * ft1[360];
    float sc = t0w * wq[j1];
    float reP = baseP + CeP1 + CoP1, imP = -(SeP1 + SoP1);
    float reT = baseT + CeT1 + CoT1, imT = -(SeT1 + SoT1);
    GG[((size_t)m * NLAT + j1) * 16 + bc] =
        make_float4(reP * sc, imP * sc, reT * sc, imT * sc);
    if (m >= 1 && m <= 179) {
      int m2 = 360 - m;
      float reP2 = baseP + CeP1 - CoP1, imP2 = SeP1 - SoP1;
      float reT2 = baseT + CeT1 - CoT1, imT2 = SeT1 - SoT1;
      GG[((size_t)m2 * NLAT + j1) * 16 + bc] =
          make_float4(reP2 * sc, imP2 * sc, reT2 * sc, imT2 * sc);
    }
  }
}

// ---------------------------------------------------------------------------
// Kernel 2: Legendre contraction + triangular PSD/cross-spectrum (R0 proven
// body). Parity symmetry Pbar_lm(-x) = (-1)^(l+m) Pbar_lm(x): only j=0..180
// of the leg table is read. Block: 256 thr = 16 bc x 4 j-lanes x 4 l-groups;
// 16 l-rows x 4 m per block. Grid: flattened triangular list, 1104 blocks.
//
// R3 change: NO global atomics. Atomic fp adds from all 8 XCDs to the 92 KB
// S buffer caused cross-XCD line ping-pong -> ~30 B HBM writeback per atomic
// (34.7 MB WRITE_SIZE, ~60% of kernel time). Each block now streams its
// 1024-float partial to a private Spart[bid] slice; red_kernel sums them.
// ---------------------------------------------------------------------------
__global__ void leg_kernel(const float* __restrict__ leg,
                           const float4* __restrict__ GG,
                           float4* __restrict__ Spart) {
  int bid = blockIdx.x;
  int lt = 0, acc = 0;
  while (bid >= acc + 4 * (lt + 1)) { acc += 4 * (lt + 1); ++lt; }
  const int l0 = lt * 16;
  const int m0 = (bid - acc) * 4;

  __shared__ float sLg[181][20];   // transposed tile, stride 20 (16B-aligned,
                                   // 2-way banks only)
  const int tid = threadIdx.x;
  const int bc  = tid >> 4;        // 0..15  (consecutive bc lanes -> full 64B lines)
  const int jl  = (tid >> 2) & 3;  // 0..3   (xor 4/8 shuffle reduction)
  const int lpg = tid & 3;         // 0..3   (l-group: rows lpg*4 .. lpg*4+3)

  float racc[4][4];
#pragma unroll
  for (int r = 0; r < 4; ++r)
#pragma unroll
    for (int c = 0; c < 4; ++c) racc[r][c] = 0.f;

  for (int mi = 0; mi < 4; ++mi) {
    const int m = m0 + mi;
    if (m > 359) break;
    if (mi) __syncthreads();
    // stage leg[l0..l0+15][m][0..180] transposed (coalesced global read)
    for (int idx = tid; idx < 16 * 181; idx += 256) {
      int lp = idx / 181, j = idx - lp * 181;
      int l = l0 + lp;
      sLg[j][lp] = (l <= 360) ? leg[((size_t)l * NLAT + m) * NLAT + j] : 0.f;
    }
    __syncthreads();

    // parity of row lpg*4+0: (l0+m)&1. u0 = A + sgn*B serves even sub-rows,
    // u1 = A - sgn*B odd sub-rows. cf halves the self-paired center j=180.
    const float sgn  = ((l0 + m) & 1) ? -1.f : 1.f;
    const float msgn = -sgn;
    float ca[4][4];
#pragma unroll
    for (int r = 0; r < 4; ++r)
#pragma unroll
      for (int c = 0; c < 4; ++c) ca[r][c] = 0.f;

    const float4* gm = GG + (size_t)m * (NLAT * 16);
#pragma unroll 2
    for (int j = jl; j <= 180; j += 4) {
      float4 A = gm[j * 16 + bc];
      float4 B = gm[(360 - j) * 16 + bc];
      float cf = (j == 180) ? 0.5f : 1.0f;
      float u0x = fmaf(sgn,  B.x, A.x) * cf, u0y = fmaf(sgn,  B.y, A.y) * cf;
      float u0z = fmaf(sgn,  B.z, A.z) * cf, u0w = fmaf(sgn,  B.w, A.w) * cf;
      float u1x = fmaf(msgn, B.x, A.x) * cf, u1y = fmaf(msgn, B.y, A.y) * cf;
      float u1z = fmaf(msgn, B.z, A.z) * cf, u1w = fmaf(msgn, B.w, A.w) * cf;
      float4 lg = *(const float4*)&sLg[j][lpg * 4];
      ca[0][0] += lg.x * u0x; ca[0][1] += lg.x * u0y;
      ca[0][2] += lg.x * u0z; ca[0][3] += lg.x * u0w;
      ca[1][0] += lg.y * u1x; ca[1][1] += lg.y * u1y;
      ca[1][2] += lg.y * u1z; ca[1][3] += lg.y * u1w;
      ca[2][0] += lg.z * u0x; ca[2][1] += lg.z * u0y;
      ca[2][2] += lg.z * u0z; ca[2][3] += lg.z * u0w;
      ca[3][0] += lg.w * u1x; ca[3][1] += lg.w * u1y;
      ca[3][2] += lg.w * u1z; ca[3][3] += lg.w * u1w;
    }
    // reduce across the 4 j-lanes (bits 2..3 of lane id)
#pragma unroll
    for (int r = 0; r < 4; ++r)
#pragma unroll
      for (int c = 0; c < 4; ++c) {
        ca[r][c] += __shfl_xor(ca[r][c], 4);
        ca[r][c] += __shfl_xor(ca[r][c], 8);
      }
    const float ef = (m == 0) ? 1.f : 2.f;
#pragma unroll
    for (int r = 0; r < 4; ++r) {
      float pr = ca[r][0], pi = ca[r][1], tr = ca[r][2], ti = ca[r][3];
      racc[r][0] += ef * (pr * pr + pi * pi);
      racc[r][1] += ef * (tr * tr + ti * ti);
      racc[r][2] += ef * (pr * tr + pi * ti);
      racc[r][3] += ef * (pr * ti - pi * tr);
    }
  }

  if (jl == 0) {
    // stream partials: Spart[bid][bc*16 + lrow] = (pp, tp, sr, si)
    float4* sp = Spart + (size_t)blockIdx.x * 256;
#pragma unroll
    for (int r = 0; r < 4; ++r) {
      int lrow = lpg * 4 + r;
      sp[bc * 16 + lrow] =
          make_float4(racc[r][0], racc[r][1], racc[r][2], racc[r][3]);
    }
  }
}

// ---------------------------------------------------------------------------
// Kernel 2b: sum per-block partials into S. One block per l-tile; each
// (bc, l, c) belongs to exactly one tile -> plain stores, no memset needed.
// Total read: 1104 * 1 KB = 4.5 MB (L2/LLC resident), ~5 us.
// ---------------------------------------------------------------------------
__global__ void red_kernel(const float* __restrict__ Spart,
                           float* __restrict__ S) {
  const int lt  = blockIdx.x;             // 0..22
  const int base = 2 * lt * (lt + 1);     // prefix of 4*(i+1)
  const int nmb  = 4 * (lt + 1);          // m-blocks in this tile
  const int tid  = threadIdx.x;           // 256
  for (int idx = tid; idx < 1024; idx += 256) {
    float s = 0.f;
    const float* p = Spart + (size_t)base * 1024 + idx;
    for (int mb = 0; mb < nmb; ++mb) s += p[(size_t)mb * 1024];
    int bc = idx >> 6, lrow = (idx >> 2) & 15, c = idx & 3;
    int l = lt * 16 + lrow;
    if (l < 360) S[((size_t)bc * 360 + l) * 4 + c] = s;
  }
}

// ---------------------------------------------------------------------------
// Kernel 3: final loss epilogue + reduction. One block.
// ---------------------------------------------------------------------------
__global__ void loss_kernel(const float* __restrict__ S,
                            const float* __restrict__ wts,
                            float* __restrict__ out) {
  const int tid = threadIdx.x;
  float acc = 0.f;
  for (int i = tid; i < 16 * 360; i += 256) {
    int bc = i / 360;
    const float* sp = S + (size_t)i * 4;
    float pp = sp[0] + EPSF;
    float tp = sp[1] + EPSF;
    float sr = sp[2], si = sp[3];
    float mag   = sqrtf(sr * sr + si * si);
    float denom = sqrtf(pp * tp + EPSF);
    float coh   = mag / (denom + EPSF);
    coh = fminf(fmaxf(coh, 0.f), 1.f);
    float sqp = sqrtf(pp), sqt = sqrtf(tp);
    float amp = (sqp - sqt) * (sqp - sqt);
    float dec = 2.f * fmaxf(pp, tp) * (1.f - coh);
    acc += (amp + dec) * wts[bc & 7];
  }
  __shared__ float red[4];
#pragma unroll
  for (int off = 32; off > 0; off >>= 1) acc += __shfl_xor(acc, off, 64);
  if ((tid & 63) == 0) red[tid >> 6] = acc;
  __syncthreads();
  if (tid == 0) {
    float loss = (red[0] + red[1] + red[2] + red[3]) / (360.f * 16.f);
    out[0] = isnan(loss) ? 1e6f : loss;
  }
}

// ---------------------------------------------------------------------------
extern "C" void kernel_launch(void* const* d_in, const int* in_sizes, int n_in,
                              void* d_out, int out_size, void* d_ws, size_t ws_size,
                              hipStream_t stream) {
  const float* pred = (const float*)d_in[0];   // [2,8,361,720]
  const float* targ = (const float*)d_in[1];   // [2,8,361,720]
  const float* wts  = (const float*)d_in[2];   // [8]
  const float* leg  = (const float*)d_in[3];   // [361,361,361]
  const float* wq   = (const float*)d_in[4];   // [361]
  float* out = (float*)d_out;

  float4* GG    = (float4*)d_ws;                              // [360][361][16] float4
  float*  S     = (float*)(GG + (size_t)360 * NLAT * 16);     // [16][360][4]
  float*  Spart = S + (size_t)16 * 360 * 4;                   // [1104][1024]

  dft_kernel<<<16 * 181, 192, 0, stream>>>(pred, targ, wq, GG);

  leg_kernel<<<1104, 256, 0, stream>>>(leg, GG, (float4*)Spart);

  red_kernel<<<23, 256, 0, stream>>>(Spart, S);

  loss_kernel<<<1, 256, 0, stream>>>(S, wts, out);
}

// Round 4
// 423.344 us; speedup vs baseline: 1.9169x; 1.1950x over previous
//
#include <hip/hip_runtime.h>
#include <math.h>

#define NLAT 361
#define NLON 720
#define EPSF 1e-7f
#define TWOPI_N 6.283185307179586e+0  // 2*pi; step = TWOPI_N/720

// ---------------------------------------------------------------------------
// Kernel 1: real DFT over longitude, two latitude rows per block (shared
// rotators), fused quadrature weight, output in leg-friendly layout:
//   GG[m][j][bc] = float4( Fp.re, Fp.im, Ft.re, Ft.im ) * (2pi/720) * w[j]
// m = 0..359 (Nyquist bin 360 is dead under the triangular mask).
// Thread m (0..180) produces bins m and 360-m via n-parity routing; per-lane
// incremental complex rotators replace the LDS twiddle table (no bank
// conflicts, no index ALU).
// ---------------------------------------------------------------------------
__global__ void dft_kernel(const float* __restrict__ pred,
                           const float* __restrict__ targ,
                           const float* __restrict__ wq,
                           float4* __restrict__ GG) {
  const int blk = blockIdx.x;          // 16 * 181 blocks
  const int bc  = blk / 181;
  const int p   = blk - bc * 181;
  const int j0  = 2 * p;
  const int j1  = (j0 + 1 <= 360) ? j0 + 1 : j0;   // row 360 pairs with itself

  const float* fp0 = pred + ((size_t)bc * NLAT + j0) * NLON;
  const float* ft0 = targ + ((size_t)bc * NLAT + j0) * NLON;
  const float* fp1 = pred + ((size_t)bc * NLAT + j1) * NLON;
  const float* ft1 = targ + ((size_t)bc * NLAT + j1) * NLON;

  __shared__ float4 eo[2][360];        // (e_p, o_p, e_t, o_t), n=1..359
  const int tid = threadIdx.x;
  for (int idx = tid; idx < 720; idx += 192) {
    int r = idx / 360, n = idx - 360 * r;
    if (n >= 1) {
      const float* a = r ? fp1 : fp0;
      const float* b = r ? ft1 : ft0;
      float a1 = a[n], a2 = a[NLON - n], b1 = b[n], b2 = b[NLON - n];
      eo[r][n] = make_float4(a1 + a2, a1 - a2, b1 + b2, b1 - b2);
    }
  }
  __syncthreads();

  const int m = tid;
  if (m > 180) return;

  // rotators: chain1 at angle (2k-1)*m*t0, chain2 at (2k)*m*t0; step 2m*t0
  float c1, s1, c2, s2, cs, ss;
  {
    float a1 = (float)(TWOPI_N / 720.0 * (double)m);
    float a2 = (float)(TWOPI_N / 720.0 * (double)(2 * m));
    sincosf(a1, &s1, &c1);
    sincosf(a2, &ss, &cs);
    c2 = cs; s2 = ss;
  }

  float CeP0 = 0.f, CoP0 = 0.f, SeP0 = 0.f, SoP0 = 0.f;
  float CeT0 = 0.f, CoT0 = 0.f, SeT0 = 0.f, SoT0 = 0.f;
  float CeP1 = 0.f, CoP1 = 0.f, SeP1 = 0.f, SoP1 = 0.f;
  float CeT1 = 0.f, CoT1 = 0.f, SeT1 = 0.f, SoT1 = 0.f;

#pragma unroll 2
  for (int k = 1; k <= 179; ++k) {
    float4 u0 = eo[0][2 * k - 1], v0 = eo[0][2 * k];
    float4 u1 = eo[1][2 * k - 1], v1 = eo[1][2 * k];
    CoP0 += u0.x * c1; SoP0 += u0.y * s1; CoT0 += u0.z * c1; SoT0 += u0.w * s1;
    CeP0 += v0.x * c2; SeP0 += v0.y * s2; CeT0 += v0.z * c2; SeT0 += v0.w * s2;
    CoP1 += u1.x * c1; SoP1 += u1.y * s1; CoT1 += u1.z * c1; SoT1 += u1.w * s1;
    CeP1 += v1.x * c2; SeP1 += v1.y * s2; CeT1 += v1.z * c2; SeT1 += v1.w * s2;
    float nc1 = c1 * cs - s1 * ss, ns1 = s1 * cs + c1 * ss;
    c1 = nc1; s1 = ns1;
    float nc2 = c2 * cs - s2 * ss, ns2 = s2 * cs + c2 * ss;
    c2 = nc2; s2 = ns2;
  }
  { // tail n = 359 (odd); c1,s1 now at angle 359*m*t0
    float4 u0 = eo[0][359], u1 = eo[1][359];
    CoP0 += u0.x * c1; SoP0 += u0.y * s1; CoT0 += u0.z * c1; SoT0 += u0.w * s1;
    CoP1 += u1.x * c1; SoP1 += u1.y * s1; CoT1 += u1.z * c1; SoT1 += u1.w * s1;
  }

  const float sgn = (m & 1) ? -1.f : 1.f;
  const float t0w = (float)(TWOPI_N / 720.0);
  // row 0
  {
    float baseP = fp0[0] + sgn * fp0[360];
    float baseT = ft0[0] + sgn * ft0[360];
    float sc = t0w * wq[j0];
    float reP = baseP + CeP0 + CoP0, imP = -(SeP0 + SoP0);
    float reT = baseT + CeT0 + CoT0, imT = -(SeT0 + SoT0);
    GG[((size_t)m * NLAT + j0) * 16 + bc] =
        make_float4(reP * sc, imP * sc, reT * sc, imT * sc);
    if (m >= 1 && m <= 179) {
      int m2 = 360 - m;
      float reP2 = baseP + CeP0 - CoP0, imP2 = SeP0 - SoP0;
      float reT2 = baseT + CeT0 - CoT0, imT2 = SeT0 - SoT0;
      GG[((size_t)m2 * NLAT + j0) * 16 + bc] =
          make_float4(reP2 * sc, imP2 * sc, reT2 * sc, imT2 * sc);
    }
  }
  // row 1 (duplicate write when j1==j0 is benign: same thread, same value)
  {
    float baseP = fp1[0] + sgn * fp1[360];
    float baseT = ft1[0] + sgn * ft1[360];
    float sc = t0w * wq[j1];
    float reP = baseP + CeP1 + CoP1, imP = -(SeP1 + SoP1);
    float reT = baseT + CeT1 + CoT1, imT = -(SeT1 + SoT1);
    GG[((size_t)m * NLAT + j1) * 16 + bc] =
        make_float4(reP * sc, imP * sc, reT * sc, imT * sc);
    if (m >= 1 && m <= 179) {
      int m2 = 360 - m;
      float reP2 = baseP + CeP1 - CoP1, imP2 = SeP1 - SoP1;
      float reT2 = baseT + CeT1 - CoT1, imT2 = SeT1 - SoT1;
      GG[((size_t)m2 * NLAT + j1) * 16 + bc] =
          make_float4(reP2 * sc, imP2 * sc, reT2 * sc, imT2 * sc);
    }
  }
}

// ---------------------------------------------------------------------------
// Kernel 2: Legendre contraction + triangular PSD/cross-spectrum (R0 proven
// body). Parity symmetry Pbar_lm(-x) = (-1)^(l+m) Pbar_lm(x): only j=0..180
// of the leg table is read. Block: 256 thr = 16 bc x 4 j-lanes x 4 l-groups.
//
// R4 change: 2 m per block (was 4) -> 2208 blocks = 8.6/CU, saturating the
// 8-block/CU residency cap (R3 measured OccupancyPercent=41% at 1104 blocks:
// grid-limited). Staging/fetch/FLOP totals unchanged. No atomics (R3): each
// block streams its partial into a private Spart[bid] slice.
// ---------------------------------------------------------------------------
__global__ void leg_kernel(const float* __restrict__ leg,
                           const float4* __restrict__ GG,
                           float4* __restrict__ Spart) {
  int bid = blockIdx.x;
  int lt = 0, acc = 0;
  while (bid >= acc + 8 * (lt + 1)) { acc += 8 * (lt + 1); ++lt; }
  const int l0 = lt * 16;
  const int m0 = (bid - acc) * 2;

  __shared__ float sLg[181][20];   // transposed tile, stride 20 (16B-aligned,
                                   // 2-way banks only)
  const int tid = threadIdx.x;
  const int bc  = tid >> 4;        // 0..15  (consecutive bc lanes -> full 64B lines)
  const int jl  = (tid >> 2) & 3;  // 0..3   (xor 4/8 shuffle reduction)
  const int lpg = tid & 3;         // 0..3   (l-group: rows lpg*4 .. lpg*4+3)

  float racc[4][4];
#pragma unroll
  for (int r = 0; r < 4; ++r)
#pragma unroll
    for (int c = 0; c < 4; ++c) racc[r][c] = 0.f;

  for (int mi = 0; mi < 2; ++mi) {
    const int m = m0 + mi;
    if (m > 359) break;            // block-uniform
    if (mi) __syncthreads();
    // stage leg[l0..l0+15][m][0..180] transposed (coalesced global read)
    for (int idx = tid; idx < 16 * 181; idx += 256) {
      int lp = idx / 181, j = idx - lp * 181;
      int l = l0 + lp;
      sLg[j][lp] = (l <= 360) ? leg[((size_t)l * NLAT + m) * NLAT + j] : 0.f;
    }
    __syncthreads();

    // parity of row lpg*4+0: (l0+m)&1. u0 = A + sgn*B serves even sub-rows,
    // u1 = A - sgn*B odd sub-rows. cf halves the self-paired center j=180.
    const float sgn  = ((l0 + m) & 1) ? -1.f : 1.f;
    const float msgn = -sgn;
    float ca[4][4];
#pragma unroll
    for (int r = 0; r < 4; ++r)
#pragma unroll
      for (int c = 0; c < 4; ++c) ca[r][c] = 0.f;

    const float4* gm = GG + (size_t)m * (NLAT * 16);
#pragma unroll 2
    for (int j = jl; j <= 180; j += 4) {
      float4 A = gm[j * 16 + bc];
      float4 B = gm[(360 - j) * 16 + bc];
      float cf = (j == 180) ? 0.5f : 1.0f;
      float u0x = fmaf(sgn,  B.x, A.x) * cf, u0y = fmaf(sgn,  B.y, A.y) * cf;
      float u0z = fmaf(sgn,  B.z, A.z) * cf, u0w = fmaf(sgn,  B.w, A.w) * cf;
      float u1x = fmaf(msgn, B.x, A.x) * cf, u1y = fmaf(msgn, B.y, A.y) * cf;
      float u1z = fmaf(msgn, B.z, A.z) * cf, u1w = fmaf(msgn, B.w, A.w) * cf;
      float4 lg = *(const float4*)&sLg[j][lpg * 4];
      ca[0][0] += lg.x * u0x; ca[0][1] += lg.x * u0y;
      ca[0][2] += lg.x * u0z; ca[0][3] += lg.x * u0w;
      ca[1][0] += lg.y * u1x; ca[1][1] += lg.y * u1y;
      ca[1][2] += lg.y * u1z; ca[1][3] += lg.y * u1w;
      ca[2][0] += lg.z * u0x; ca[2][1] += lg.z * u0y;
      ca[2][2] += lg.z * u0z; ca[2][3] += lg.z * u0w;
      ca[3][0] += lg.w * u1x; ca[3][1] += lg.w * u1y;
      ca[3][2] += lg.w * u1z; ca[3][3] += lg.w * u1w;
    }
    // reduce across the 4 j-lanes (bits 2..3 of lane id)
#pragma unroll
    for (int r = 0; r < 4; ++r)
#pragma unroll
      for (int c = 0; c < 4; ++c) {
        ca[r][c] += __shfl_xor(ca[r][c], 4);
        ca[r][c] += __shfl_xor(ca[r][c], 8);
      }
    const float ef = (m == 0) ? 1.f : 2.f;
#pragma unroll
    for (int r = 0; r < 4; ++r) {
      float pr = ca[r][0], pi = ca[r][1], tr = ca[r][2], ti = ca[r][3];
      racc[r][0] += ef * (pr * pr + pi * pi);
      racc[r][1] += ef * (tr * tr + ti * ti);
      racc[r][2] += ef * (pr * tr + pi * ti);
      racc[r][3] += ef * (pr * ti - pi * tr);
    }
  }

  if (jl == 0) {
    // stream partials: Spart[bid][bc*16 + lrow] = (pp, tp, sr, si)
    float4* sp = Spart + (size_t)blockIdx.x * 256;
#pragma unroll
    for (int r = 0; r < 4; ++r) {
      int lrow = lpg * 4 + r;
      sp[bc * 16 + lrow] =
          make_float4(racc[r][0], racc[r][1], racc[r][2], racc[r][3]);
    }
  }
}

// ---------------------------------------------------------------------------
// Kernel 2b: sum per-block partials into S.
// R4 change: 92 blocks (4 per l-tile, one thread per output element) + 4
// independent accumulators -> >=4 loads in flight. R3's 23-block version with
// a single serial accumulator chain was ~95 us of pure load latency.
// Lanes read consecutive idx -> each mb row is one coalesced 1KB wave read.
// nmb = 8*(lt+1) is always divisible by 4.
// ---------------------------------------------------------------------------
__global__ void red_kernel(const float* __restrict__ Spart,
                           float* __restrict__ S) {
  const int b    = blockIdx.x;            // 0..91
  const int lt   = b >> 2;                // 0..22
  const int base = 4 * lt * (lt + 1);     // prefix of 8*(i+1)
  const int nmb  = 8 * (lt + 1);          // m-blocks in this tile
  const int idx  = ((b & 3) << 8) | threadIdx.x;   // 0..1023

  const float* p = Spart + (size_t)base * 1024 + idx;
  float s0 = 0.f, s1 = 0.f, s2 = 0.f, s3 = 0.f;
  for (int mb = 0; mb < nmb; mb += 4) {
    s0 += p[(size_t)(mb + 0) * 1024];
    s1 += p[(size_t)(mb + 1) * 1024];
    s2 += p[(size_t)(mb + 2) * 1024];
    s3 += p[(size_t)(mb + 3) * 1024];
  }
  float s = (s0 + s1) + (s2 + s3);
  int bc = idx >> 6, lrow = (idx >> 2) & 15, c = idx & 3;
  int l = lt * 16 + lrow;
  if (l < 360) S[((size_t)bc * 360 + l) * 4 + c] = s;
}

// ---------------------------------------------------------------------------
// Kernel 3: final loss epilogue + reduction. One block.
// ---------------------------------------------------------------------------
__global__ void loss_kernel(const float* __restrict__ S,
                            const float* __restrict__ wts,
                            float* __restrict__ out) {
  const int tid = threadIdx.x;
  float acc = 0.f;
  for (int i = tid; i < 16 * 360; i += 256) {
    int bc = i / 360;
    const float* sp = S + (size_t)i * 4;
    float pp = sp[0] + EPSF;
    float tp = sp[1] + EPSF;
    float sr = sp[2], si = sp[3];
    float mag   = sqrtf(sr * sr + si * si);
    float denom = sqrtf(pp * tp + EPSF);
    float coh   = mag / (denom + EPSF);
    coh = fminf(fmaxf(coh, 0.f), 1.f);
    float sqp = sqrtf(pp), sqt = sqrtf(tp);
    float amp = (sqp - sqt) * (sqp - sqt);
    float dec = 2.f * fmaxf(pp, tp) * (1.f - coh);
    acc += (amp + dec) * wts[bc & 7];
  }
  __shared__ float red[4];
#pragma unroll
  for (int off = 32; off > 0; off >>= 1) acc += __shfl_xor(acc, off, 64);
  if ((tid & 63) == 0) red[tid >> 6] = acc;
  __syncthreads();
  if (tid == 0) {
    float loss = (red[0] + red[1] + red[2] + red[3]) / (360.f * 16.f);
    out[0] = isnan(loss) ? 1e6f : loss;
  }
}

// ---------------------------------------------------------------------------
extern "C" void kernel_launch(void* const* d_in, const int* in_sizes, int n_in,
                              void* d_out, int out_size, void* d_ws, size_t ws_size,
                              hipStream_t stream) {
  const float* pred = (const float*)d_in[0];   // [2,8,361,720]
  const float* targ = (const float*)d_in[1];   // [2,8,361,720]
  const float* wts  = (const float*)d_in[2];   // [8]
  const float* leg  = (const float*)d_in[3];   // [361,361,361]
  const float* wq   = (const float*)d_in[4];   // [361]
  float* out = (float*)d_out;

  float4* GG    = (float4*)d_ws;                              // [360][361][16] float4
  float*  S     = (float*)(GG + (size_t)360 * NLAT * 16);     // [16][360][4]
  float*  Spart = S + (size_t)16 * 360 * 4;                   // [2208][1024]

  dft_kernel<<<16 * 181, 192, 0, stream>>>(pred, targ, wq, GG);

  // 2208 = sum over 23 l-tiles of 8*(lt+1) two-m blocks
  leg_kernel<<<2208, 256, 0, stream>>>(leg, GG, (float4*)Spart);

  red_kernel<<<92, 256, 0, stream>>>(Spart, S);

  loss_kernel<<<1, 256, 0, stream>>>(S, wts, out);
}